// Round 1
// 626.094 us; speedup vs baseline: 1.1253x; 1.1253x over previous
//
#include <hip/hip_runtime.h>
#include <stdint.h>

// GIN GNN: N=40000, E=640000, H=128, 5 layers, PROJ=256.
// R9: aggregate gather source switched fp32 -> bf16. BN+relu of the previous
// layer is now materialized once per layer into hbn (bf16, 256B/row) by a
// cheap streaming pass (bnrelu_k), instead of being applied per-edge on
// 512B fp32 gathers. Halves gather demand bytes AND working set (20.5->10.2MB,
// better L2 hit rate). atom_encode writes bf16 directly (layer 0 has no BN).

typedef unsigned short ushort_t;
typedef unsigned int uint_t;
typedef __attribute__((ext_vector_type(8))) short bf16x8;
typedef __attribute__((ext_vector_type(16))) float f32x16;

#define MFMA32(a, b, c) __builtin_amdgcn_mfma_f32_32x32x16_bf16(a, b, c, 0, 0, 0)

__device__ inline ushort_t f2bf(float f) {
  uint_t u = __builtin_bit_cast(uint_t, f);
  u += 0x7FFFu + ((u >> 16) & 1u);
  return (ushort_t)(u >> 16);
}
__device__ inline float bf2f(uint_t h) {  // low 16 bits
  uint_t u = (h & 0xFFFFu) << 16;
  return __builtin_bit_cast(float, u);
}
__device__ inline uint_t pack2(float a, float b) {
  return (uint_t)f2bf(a) | ((uint_t)f2bf(b) << 16);
}
__device__ inline f32x16 zero16() {
  f32x16 z;
#pragma unroll
  for (int i = 0; i < 16; ++i) z[i] = 0.f;
  return z;
}

// ---------- precompute ----------

// comb[l][c][128] bf16, c = a0|a1<<4|a2<<8
__global__ __launch_bounds__(256) void bond_comb_k(
    const float* __restrict__ bemb, ushort_t* __restrict__ comb)
{
  int idx = blockIdx.x * 256 + threadIdx.x;  // over 5*4096*64
  if (idx >= 5 * 4096 * 64) return;
  int lane = idx & 63, c = (idx >> 6) & 4095, l = idx >> 18;
  const float2* b2 = (const float2*)(bemb + (size_t)l * 3 * 16 * 128);
  float2 e0 = b2[(c & 15) * 64 + lane];
  float2 e1 = b2[(16 + ((c >> 4) & 15)) * 64 + lane];
  float2 e2 = b2[(32 + (c >> 8)) * 64 + lane];
  ((uint_t*)comb)[idx] = pack2(e0.x + e1.x + e2.x, e0.y + e1.y + e2.y);
}

// All 11 weight swizzles in one launch. m<6: K=128,N=256 (w1 x5, linw);
// m>=6: K=256,N=128 (w2 x5).
__global__ __launch_bounds__(256) void swz_all_k(
    const float* __restrict__ w1, const float* __restrict__ linw,
    const float* __restrict__ w2, ushort_t* __restrict__ bswz1,
    ushort_t* __restrict__ bswz2)
{
  int t = blockIdx.x * 256 + threadIdx.x;  // 11*4096
  if (t >= 11 * 4096) return;
  int m = t >> 12, tt = t & 4095, lane = tt & 63;
  if (m < 6) {
    const float* w = (m < 5) ? (w1 + (size_t)m * 32768) : linw;
    ushort_t* o = bswz1 + (size_t)m * 32768;
    int nt = (tt >> 6) & 7, s = tt >> 9;
    int kb = s * 16 + (lane >> 5) * 8, n = nt * 32 + (lane & 31);
    ushort_t tmp[8];
#pragma unroll
    for (int j = 0; j < 8; ++j) tmp[j] = f2bf(w[(size_t)(kb + j) * 256 + n]);
    ((uint4*)o)[tt] = *(uint4*)tmp;
  } else {
    int mm = m - 6;
    const float* w = w2 + (size_t)mm * 32768;
    ushort_t* o = bswz2 + (size_t)mm * 32768;
    int nt = (tt >> 6) & 3, s = tt >> 8;
    int kb = s * 16 + (lane >> 5) * 8, n = nt * 32 + (lane & 31);
    ushort_t tmp[8];
#pragma unroll
    for (int j = 0; j < 8; ++j) tmp[j] = f2bf(w[(size_t)(kb + j) * 128 + n]);
    ((uint4*)o)[tt] = *(uint4*)tmp;
  }
}

// ---------- graph preprocessing ----------

__global__ void zero_int_k(int* p, int n) {
  int i = blockIdx.x * 256 + threadIdx.x;
  if (i < n) p[i] = 0;
}

__global__ void hist_k(const int* __restrict__ ei, int* __restrict__ cnt, int E) {
  int e = blockIdx.x * 256 + threadIdx.x;
  if (e >= E) return;
  atomicAdd(&cnt[ei[E + e]], 1);
}

__global__ __launch_bounds__(256) void block_sum_k(
    const int* __restrict__ cnt, int* __restrict__ bsum, int N)
{
  __shared__ int red[256];
  int t = threadIdx.x, idx = blockIdx.x * 256 + t;
  red[t] = (idx < N) ? cnt[idx] : 0;
  __syncthreads();
  for (int o = 128; o > 0; o >>= 1) {
    if (t < o) red[t] += red[t + o];
    __syncthreads();
  }
  if (t == 0) bsum[blockIdx.x] = red[0];
}

__global__ __launch_bounds__(256) void scan_bsum_k(
    int* __restrict__ bsum, int* __restrict__ rsN, int nb)
{
  __shared__ int s[256];
  int t = threadIdx.x;
  s[t] = (t < nb) ? bsum[t] : 0;
  __syncthreads();
  for (int o = 1; o < 256; o <<= 1) {
    int v = (t >= o) ? s[t - o] : 0;
    __syncthreads();
    s[t] += v;
    __syncthreads();
  }
  if (t < nb) bsum[t] = (t == 0) ? 0 : s[t - 1];
  if (t == nb - 1) *rsN = s[t];
}

__global__ __launch_bounds__(256) void scan_write_k(
    const int* __restrict__ cnt, const int* __restrict__ bsum,
    int* __restrict__ rs, int* __restrict__ cursor, int N)
{
  __shared__ int s[256];
  int t = threadIdx.x, idx = blockIdx.x * 256 + t;
  int v = (idx < N) ? cnt[idx] : 0;
  s[t] = v;
  __syncthreads();
  for (int o = 1; o < 256; o <<= 1) {
    int u = (t >= o) ? s[t - o] : 0;
    __syncthreads();
    s[t] += u;
    __syncthreads();
  }
  int excl = s[t] - v + bsum[blockIdx.x];
  if (idx < N) { rs[idx] = excl; cursor[idx] = excl; }
}

__global__ void scatter_k(const int* __restrict__ ei, const int* __restrict__ ea,
                          int* __restrict__ cursor, uint32_t* __restrict__ sorted, int E)
{
  int e = blockIdx.x * 256 + threadIdx.x;
  if (e >= E) return;
  int src = ei[e], dst = ei[E + e];
  int a0 = ea[e * 3], a1 = ea[e * 3 + 1], a2 = ea[e * 3 + 2];
  int pos = atomicAdd(&cursor[dst], 1);
  sorted[pos] = (uint32_t)src | ((uint32_t)a0 << 16) | ((uint32_t)a1 << 20) | ((uint32_t)a2 << 24);
}

// ---------- node pipeline ----------

// Layer-0 h (no BN): write bf16 directly into hbn.
__global__ __launch_bounds__(256) void atom_encode_k(
    const int* __restrict__ x, const float* __restrict__ aemb,
    ushort_t* __restrict__ hbn, int N)
{
  int idx = blockIdx.x * 256 + threadIdx.x;
  if (idx >= N * 64) return;
  int n = idx >> 6, lane = idx & 63;
  const int* xr = x + n * 9;
  float sx = 0.f, sy = 0.f;
#pragma unroll
  for (int f = 0; f < 9; ++f) {
    float2 e = ((const float2*)(aemb + (size_t)(f * 128 + xr[f]) * 128))[lane];
    sx += e.x; sy += e.y;
  }
  ((uint_t*)hbn)[idx] = pack2(sx, sy);
}

// Materialize hbn = relu(BN(raw)) as bf16, once per layer (layers 1..4).
// Grid-stride; lane (channel pair) constant per thread so BN params are
// computed once.
__global__ __launch_bounds__(256) void bnrelu_k(
    const float* __restrict__ raw, const float* __restrict__ stats2,
    const float* __restrict__ g, const float* __restrict__ bb,
    ushort_t* __restrict__ hbn, float invN, int total)
{
  int t = blockIdx.x * 256 + threadIdx.x;
  int lane = t & 63;
  int c0 = 2 * lane, c1 = c0 + 1;
  float mu0 = stats2[c0] * invN, mu1 = stats2[c1] * invN;
  float v0 = stats2[128 + c0] * invN - mu0 * mu0;
  float v1 = stats2[128 + c1] * invN - mu1 * mu1;
  float scx = rsqrtf(v0 + 1e-5f) * g[c0];
  float scy = rsqrtf(v1 + 1e-5f) * g[c1];
  float shx = bb[c0] - mu0 * scx;
  float shy = bb[c1] - mu1 * scy;
  int stride = gridDim.x * 256;
  for (int idx = t; idx < total; idx += stride) {
    float2 h = ((const float2*)raw)[idx];
    float hx = fmaxf(fmaf(h.x, scx, shx), 0.f);
    float hy = fmaxf(fmaf(h.y, scy, shy), 0.f);
    ((uint_t*)hbn)[idx] = pack2(hx, hy);
  }
}

// One wave per node; 256B bf16 row gathers (dword/lane).
// zin(bf16) = (1+eps)*hbn + sum_e relu(hbn[src] + comb[c]).
// Edge loop pipelined x16 (all 33 loads issued before first consume).
// Block 0 zeroes stats[0..511] (BN1 accums).
__global__ __launch_bounds__(256) void aggregate_k(
    const ushort_t* __restrict__ hbn, const ushort_t* __restrict__ comb,
    const uint32_t* __restrict__ sorted, const int* __restrict__ rs,
    const float* __restrict__ eps, int layer, ushort_t* __restrict__ zin,
    float* __restrict__ stats, int N)
{
  if (blockIdx.x == 0) {
    stats[threadIdx.x] = 0.f;
    stats[threadIdx.x + 256] = 0.f;
  }
  int wave = threadIdx.x >> 6, lane = threadIdx.x & 63;
  int n = blockIdx.x * 4 + wave;
  if (n >= N) return;
  int beg = rs[n], end = rs[n + 1];
  const uint_t* hb = (const uint_t*)hbn;
  const uint_t* cb = ((const uint_t*)comb) + (size_t)layer * 4096 * 64;
  float ax = 0.f, ay = 0.f;
  int i = beg;
  for (; i + 16 <= end; i += 16) {
    uint32_t p[16];
#pragma unroll
    for (int j = 0; j < 16; ++j) p[j] = sorted[i + j];
    uint_t hv[16], ee[16];
#pragma unroll
    for (int j = 0; j < 16; ++j) {
      hv[j] = hb[(size_t)(p[j] & 0xFFFFu) * 64 + lane];
      ee[j] = cb[(p[j] >> 16) * 64 + lane];
    }
#pragma unroll
    for (int j = 0; j < 16; ++j) {
      ax += fmaxf(bf2f(hv[j]) + bf2f(ee[j]), 0.f);
      ay += fmaxf(bf2f(hv[j] >> 16) + bf2f(ee[j] >> 16), 0.f);
    }
  }
  for (; i + 4 <= end; i += 4) {
    uint32_t p[4];
#pragma unroll
    for (int j = 0; j < 4; ++j) p[j] = sorted[i + j];
    uint_t hv[4], ee[4];
#pragma unroll
    for (int j = 0; j < 4; ++j) {
      hv[j] = hb[(size_t)(p[j] & 0xFFFFu) * 64 + lane];
      ee[j] = cb[(p[j] >> 16) * 64 + lane];
    }
#pragma unroll
    for (int j = 0; j < 4; ++j) {
      ax += fmaxf(bf2f(hv[j]) + bf2f(ee[j]), 0.f);
      ay += fmaxf(bf2f(hv[j] >> 16) + bf2f(ee[j] >> 16), 0.f);
    }
  }
  for (; i < end; ++i) {
    uint32_t p = sorted[i];
    uint_t ee = cb[(p >> 16) * 64 + lane];
    uint_t hv = hb[(size_t)(p & 0xFFFFu) * 64 + lane];
    ax += fmaxf(bf2f(hv) + bf2f(ee), 0.f);
    ay += fmaxf(bf2f(hv >> 16) + bf2f(ee >> 16), 0.f);
  }
  float s = 1.f + eps[layer];
  uint_t hn = hb[(size_t)n * 64 + lane];
  ((uint_t*)zin)[(size_t)n * 64 + lane] =
      pack2(fmaf(s, bf2f(hn), ax), fmaf(s, bf2f(hn >> 16), ay));
}

// ---------- MFMA GEMMs ----------
// A staged in LDS, XOR-swizzled in 16B chunks: elem (r,k) at col
// ((k>>3)^(r&15))*8 + (k&7).   Frags: A[m=lane&31][k=(lane>>5)*8+j],
// B[k][n=lane&31][k=(lane>>5)*8+j] (pre-swizzled),
// C/D col=lane&31, row=(reg&3)+8*(reg>>2)+4*(lane>>5).

// Kernel A: GEMM1 [64,128]@[128,256]+b1, emits ONLY column sum/sumsq into
// statsOut (BN1 accums). Block 0 zeroes stats2 region (256 floats).
__global__ __launch_bounds__(256) void gemm1_stats_k(
    const ushort_t* __restrict__ in, const ushort_t* __restrict__ bswz,
    const float* __restrict__ bias, float* __restrict__ statsOut,
    float* __restrict__ zeroPtr)
{
  __shared__ ushort_t As[64 * 128];
  int tid = threadIdx.x;
  int wave = tid >> 6, lane = tid & 63;
  int lr = lane & 31, half = lane >> 5;
  int row0 = blockIdx.x * 64;
  if (blockIdx.x == 0) zeroPtr[tid] = 0.f;
  {
    const uint2* src = (const uint2*)(in + (size_t)row0 * 128);
#pragma unroll
    for (int i = 0; i < 8; ++i) {
      int idx = tid + 256 * i;
      int r = idx >> 5, c = (idx & 31) * 4;
      uint2 v = src[idx];
      int scol = (((c >> 3) ^ (r & 15)) << 3) | (c & 7);
      *(uint2*)&As[r * 128 + scol] = v;
    }
  }
  __syncthreads();
  int nt0 = wave * 2, nt1 = nt0 + 1;
  f32x16 acc00 = zero16(), acc01 = zero16(), acc10 = zero16(), acc11 = zero16();
  const bf16x8* Bp = (const bf16x8*)bswz;
#pragma unroll
  for (int s = 0; s < 8; ++s) {
    int k = s * 16 + half * 8;
    int scol = ((k >> 3) ^ (lr & 15)) << 3;
    bf16x8 a0 = *(const bf16x8*)&As[lr * 128 + scol];
    bf16x8 a1 = *(const bf16x8*)&As[(32 + lr) * 128 + scol];
    bf16x8 b0 = Bp[(s * 8 + nt0) * 64 + lane];
    bf16x8 b1 = Bp[(s * 8 + nt1) * 64 + lane];
    acc00 = MFMA32(a0, b0, acc00);
    acc10 = MFMA32(a1, b0, acc10);
    acc01 = MFMA32(a0, b1, acc01);
    acc11 = MFMA32(a1, b1, acc11);
  }
  int col0 = nt0 * 32 + lr, col1 = nt1 * 32 + lr;
  float bv0 = bias[col0], bv1 = bias[col1];
  float s0 = 0, q0 = 0, s1 = 0, q1 = 0;
#pragma unroll
  for (int r2 = 0; r2 < 16; ++r2) {
    float v00 = acc00[r2] + bv0, v10 = acc10[r2] + bv0;
    float v01 = acc01[r2] + bv1, v11 = acc11[r2] + bv1;
    s0 += v00 + v10; q0 += v00 * v00 + v10 * v10;
    s1 += v01 + v11; q1 += v01 * v01 + v11 * v11;
  }
  s0 += __shfl_xor(s0, 32); q0 += __shfl_xor(q0, 32);
  s1 += __shfl_xor(s1, 32); q1 += __shfl_xor(q1, 32);
  if (lane < 32) {
    atomicAdd(&statsOut[col0], s0);
    atomicAdd(&statsOut[256 + col0], q0);
    atomicAdd(&statsOut[col1], s1);
    atomicAdd(&statsOut[256 + col1], q1);
  }
}

// Kernel B: recompute GEMM1, BN1+relu in-register (b1 folded into shift),
// C->A relayout via LDS (bf16), GEMM2 [64,256]@[256,128]+b2 -> raw fp32,
// accumulate BN2 stats.
__global__ __launch_bounds__(256) void fused_mlp_k(
    const ushort_t* __restrict__ in, const ushort_t* __restrict__ bswz1,
    const float* __restrict__ b1, const float* __restrict__ stats1,
    const float* __restrict__ g1, const float* __restrict__ bb1,
    const ushort_t* __restrict__ bswz2, const float* __restrict__ b2,
    float* __restrict__ outf, float* __restrict__ stats2, float invN)
{
  __shared__ ushort_t As[64 * 128];   // zin staging (16 KB)
  __shared__ ushort_t Bs[64 * 256];   // post-BN1 z1 tile (32 KB)
  __shared__ float sc1[256], sh1[256];
  int tid = threadIdx.x;
  int wave = tid >> 6, lane = tid & 63;
  int lr = lane & 31, half = lane >> 5;
  int row0 = blockIdx.x * 64;
  {
    int c = tid;
    float mu = stats1[c] * invN;
    float var = stats1[256 + c] * invN - mu * mu;
    float r = rsqrtf(var + 1e-5f) * g1[c];
    sc1[c] = r;
    sh1[c] = bb1[c] - mu * r + b1[c] * r;   // fold bias1 into shift
  }
  {
    const uint2* src = (const uint2*)(in + (size_t)row0 * 128);
#pragma unroll
    for (int i = 0; i < 8; ++i) {
      int idx = tid + 256 * i;
      int r = idx >> 5, c = (idx & 31) * 4;
      uint2 v = src[idx];
      int scol = (((c >> 3) ^ (r & 15)) << 3) | (c & 7);
      *(uint2*)&As[r * 128 + scol] = v;
    }
  }
  __syncthreads();
  int nt0 = wave * 2, nt1 = nt0 + 1;
  f32x16 acc00 = zero16(), acc01 = zero16(), acc10 = zero16(), acc11 = zero16();
  {
    const bf16x8* Bp = (const bf16x8*)bswz1;
#pragma unroll
    for (int s = 0; s < 8; ++s) {
      int k = s * 16 + half * 8;
      int scol = ((k >> 3) ^ (lr & 15)) << 3;
      bf16x8 a0 = *(const bf16x8*)&As[lr * 128 + scol];
      bf16x8 a1 = *(const bf16x8*)&As[(32 + lr) * 128 + scol];
      bf16x8 b0v = Bp[(s * 8 + nt0) * 64 + lane];
      bf16x8 b1v = Bp[(s * 8 + nt1) * 64 + lane];
      acc00 = MFMA32(a0, b0v, acc00);
      acc10 = MFMA32(a1, b0v, acc10);
      acc01 = MFMA32(a0, b1v, acc01);
      acc11 = MFMA32(a1, b1v, acc11);
    }
  }
  {
    int col0 = nt0 * 32 + lr, col1 = nt1 * 32 + lr;
    float sc0v = sc1[col0], sh0v = sh1[col0];
    float sc1v = sc1[col1], sh1v = sh1[col1];
    auto wr = [&](const f32x16& a, int mtb, int col, float scv, float shv) {
#pragma unroll
      for (int r2 = 0; r2 < 16; ++r2) {
        int row = mtb + (r2 & 3) + 8 * (r2 >> 2) + 4 * half;
        float v = fmaxf(fmaf(a[r2], scv, shv), 0.f);
        int scol = (((col >> 3) ^ (row & 15)) << 3) | (col & 7);
        Bs[row * 256 + scol] = f2bf(v);
      }
    };
    wr(acc00, 0, col0, sc0v, sh0v);
    wr(acc10, 32, col0, sc0v, sh0v);
    wr(acc01, 0, col1, sc1v, sh1v);
    wr(acc11, 32, col1, sc1v, sh1v);
  }
  __syncthreads();
  f32x16 acc0 = zero16(), acc1 = zero16();
  {
    const bf16x8* Bp2 = (const bf16x8*)bswz2;
#pragma unroll
    for (int s = 0; s < 16; ++s) {
      int k = s * 16 + half * 8;
      int scol = ((k >> 3) ^ (lr & 15)) << 3;
      bf16x8 a0 = *(const bf16x8*)&Bs[lr * 256 + scol];
      bf16x8 a1 = *(const bf16x8*)&Bs[(32 + lr) * 256 + scol];
      bf16x8 b = Bp2[(s * 4 + wave) * 64 + lane];
      acc0 = MFMA32(a0, b, acc0);
      acc1 = MFMA32(a1, b, acc1);
    }
  }
  int col = wave * 32 + lr;
  float bv = b2[col];
  float s0 = 0, q0 = 0;
  auto emit = [&](const f32x16& a, int mtb) {
#pragma unroll
    for (int r2 = 0; r2 < 16; ++r2) {
      int row = row0 + mtb + (r2 & 3) + 8 * (r2 >> 2) + 4 * half;
      float v = a[r2] + bv;
      outf[(size_t)row * 128 + col] = v;
      s0 += v;
      q0 += v * v;
    }
  };
  emit(acc0, 0);
  emit(acc1, 32);
  s0 += __shfl_xor(s0, 32);
  q0 += __shfl_xor(q0, 32);
  if (lane < 32) {
    atomicAdd(&stats2[col], s0);
    atomicAdd(&stats2[128 + col], q0);
  }
}

// Final projection: BN(stats2) on fp32 raw at load (no relu), then
// [64,128]@[128,256]+linb -> fp32 out.
__global__ __launch_bounds__(256) void final_proj_k(
    const float* __restrict__ inf, const ushort_t* __restrict__ bswz,
    const float* __restrict__ bias, const float* __restrict__ stats2,
    const float* __restrict__ g, const float* __restrict__ bb,
    float* __restrict__ outf, float invN)
{
  __shared__ ushort_t As[64 * 128];
  __shared__ float sc[128], sh[128];
  int tid = threadIdx.x;
  int wave = tid >> 6, lane = tid & 63;
  int lr = lane & 31, half = lane >> 5;
  int row0 = blockIdx.x * 64;
  if (tid < 128) {
    int c = tid;
    float mu = stats2[c] * invN;
    float var = stats2[128 + c] * invN - mu * mu;
    float r = rsqrtf(var + 1e-5f) * g[c];
    sc[c] = r;
    sh[c] = bb[c] - mu * r;
  }
  __syncthreads();
  {
    const float4* src = (const float4*)(inf + (size_t)row0 * 128);
#pragma unroll
    for (int i = 0; i < 8; ++i) {
      int idx = tid + 256 * i;
      int r = idx >> 5, c = (idx & 31) * 4;
      float4 v = src[idx];
      v.x = fmaf(v.x, sc[c], sh[c]);
      v.y = fmaf(v.y, sc[c + 1], sh[c + 1]);
      v.z = fmaf(v.z, sc[c + 2], sh[c + 2]);
      v.w = fmaf(v.w, sc[c + 3], sh[c + 3]);
      uint2 o;
      o.x = pack2(v.x, v.y);
      o.y = pack2(v.z, v.w);
      int scol = (((c >> 3) ^ (r & 15)) << 3) | (c & 7);
      *(uint2*)&As[r * 128 + scol] = o;
    }
  }
  __syncthreads();
  int nt0 = wave * 2, nt1 = nt0 + 1;
  f32x16 acc00 = zero16(), acc01 = zero16(), acc10 = zero16(), acc11 = zero16();
  const bf16x8* Bp = (const bf16x8*)bswz;
#pragma unroll
  for (int s = 0; s < 8; ++s) {
    int k = s * 16 + half * 8;
    int scol = ((k >> 3) ^ (lr & 15)) << 3;
    bf16x8 a0 = *(const bf16x8*)&As[lr * 128 + scol];
    bf16x8 a1 = *(const bf16x8*)&As[(32 + lr) * 128 + scol];
    bf16x8 b0 = Bp[(s * 8 + nt0) * 64 + lane];
    bf16x8 b1 = Bp[(s * 8 + nt1) * 64 + lane];
    acc00 = MFMA32(a0, b0, acc00);
    acc10 = MFMA32(a1, b0, acc10);
    acc01 = MFMA32(a0, b1, acc01);
    acc11 = MFMA32(a1, b1, acc11);
  }
  int col0 = nt0 * 32 + lr, col1 = nt1 * 32 + lr;
  float bv0 = bias[col0], bv1 = bias[col1];
  auto emit = [&](const f32x16& a, int mtb, int col, float bv) {
#pragma unroll
    for (int r2 = 0; r2 < 16; ++r2) {
      int row = row0 + mtb + (r2 & 3) + 8 * (r2 >> 2) + 4 * half;
      outf[(size_t)row * 256 + col] = a[r2] + bv;
    }
  };
  emit(acc00, 0, col0, bv0);
  emit(acc10, 32, col0, bv0);
  emit(acc01, 0, col1, bv1);
  emit(acc11, 32, col1, bv1);
}

extern "C" void kernel_launch(void* const* d_in, const int* in_sizes, int n_in,
                              void* d_out, int out_size, void* d_ws, size_t ws_size,
                              hipStream_t stream)
{
  const int* x = (const int*)d_in[0];
  const int* ei = (const int*)d_in[1];
  const int* ea = (const int*)d_in[2];
  const float* aemb = (const float*)d_in[3];
  const float* bemb = (const float*)d_in[4];
  const float* eps = (const float*)d_in[5];
  const float* w1 = (const float*)d_in[6];
  const float* b1 = (const float*)d_in[7];
  const float* bn1g = (const float*)d_in[8];
  const float* bn1b = (const float*)d_in[9];
  const float* w2 = (const float*)d_in[10];
  const float* b2 = (const float*)d_in[11];
  const float* bng = (const float*)d_in[12];
  const float* bnb = (const float*)d_in[13];
  const float* linw = (const float*)d_in[14];
  const float* linb = (const float*)d_in[15];
  int N = in_sizes[0] / 9;   // 40000
  int E = in_sizes[1] / 2;   // 640000
  int nb = (N + 255) / 256;

  char* ws = (char*)d_ws;
  size_t off = 0;
  auto alloc = [&](size_t bytes) {
    void* p = ws + off;
    off += (bytes + 255) & ~(size_t)255;
    return p;
  };
  float* raw = (float*)alloc((size_t)N * 128 * 4);         // pre-BN z2, fp32
  ushort_t* hbn = (ushort_t*)alloc((size_t)N * 128 * 2);   // post-BN h, bf16
  ushort_t* zin = (ushort_t*)alloc((size_t)N * 128 * 2);   // GEMM1 input, bf16
  ushort_t* comb = (ushort_t*)alloc((size_t)5 * 4096 * 128 * 2);
  ushort_t* bswz1 = (ushort_t*)alloc((size_t)6 * 32768 * 2);  // 5x w1 + linw
  ushort_t* bswz2 = (ushort_t*)alloc((size_t)5 * 32768 * 2);
  uint32_t* sorted = (uint32_t*)alloc((size_t)E * 4);
  int* rs = (int*)alloc((size_t)(N + 1) * 4);
  int* cursor = (int*)alloc((size_t)N * 4);
  int* cnt = (int*)alloc((size_t)N * 4);
  int* bsum = (int*)alloc((size_t)nb * 4);
  float* stats = (float*)alloc(768 * 4);  // [sum1:256][sq1:256][sum2:128][sq2:128]
  float invN = 1.f / (float)N;

  bond_comb_k<<<(5 * 4096 * 64 + 255) / 256, 256, 0, stream>>>(bemb, comb);
  swz_all_k<<<(11 * 4096 + 255) / 256, 256, 0, stream>>>(w1, linw, w2, bswz1, bswz2);

  atom_encode_k<<<(N * 64 + 255) / 256, 256, 0, stream>>>(x, aemb, hbn, N);
  zero_int_k<<<(N + 255) / 256, 256, 0, stream>>>(cnt, N);
  hist_k<<<(E + 255) / 256, 256, 0, stream>>>(ei, cnt, E);
  block_sum_k<<<nb, 256, 0, stream>>>(cnt, bsum, N);
  scan_bsum_k<<<1, 256, 0, stream>>>(bsum, rs + N, nb);
  scan_write_k<<<nb, 256, 0, stream>>>(cnt, bsum, rs, cursor, N);
  scatter_k<<<(E + 255) / 256, 256, 0, stream>>>(ei, ea, cursor, sorted, E);

  for (int l = 0; l < 5; ++l) {
    if (l > 0) {
      bnrelu_k<<<2048, 256, 0, stream>>>(
          raw, stats + 512, bng + (size_t)(l - 1) * 128,
          bnb + (size_t)(l - 1) * 128, hbn, invN, N * 64);
    }
    aggregate_k<<<(N + 3) / 4, 256, 0, stream>>>(
        hbn, comb, sorted, rs, eps, l, zin, stats, N);
    gemm1_stats_k<<<N / 64, 256, 0, stream>>>(
        zin, bswz1 + (size_t)l * 32768, b1 + (size_t)l * 256,
        stats, stats + 512);
    fused_mlp_k<<<N / 64, 256, 0, stream>>>(
        zin, bswz1 + (size_t)l * 32768, b1 + (size_t)l * 256,
        stats, bn1g + (size_t)l * 256, bn1b + (size_t)l * 256,
        bswz2 + (size_t)l * 32768, b2 + (size_t)l * 128,
        raw, stats + 512, invN);
  }
  final_proj_k<<<N / 64, 256, 0, stream>>>(
      raw, bswz1 + (size_t)5 * 32768, linb, stats + 512,
      bng + (size_t)4 * 128, bnb + (size_t)4 * 128, (float*)d_out, invN);
}

// Round 4
// 622.732 us; speedup vs baseline: 1.1314x; 1.0054x over previous
//
#include <hip/hip_runtime.h>
#include <stdint.h>

// GIN GNN: N=40000, E=640000, H=128, 5 layers, PROJ=256.
// R12: R10/R11 failures diagnosed as workspace overflow (R9=50MB passed;
// R10=62MB, R11=82MB failed with run-dependent absmax 468 vs 0.13).
// Fix: z1 stored bf16 ALIASED onto raw (per-block byte-matched: mlp2 block b
// reads z1 bytes [b*32K,(b+1)*32K) into LDS, then writes raw fp32 to the same
// bytes; disjoint across blocks). Footprint now 39.7MB. Precision margin for
// z1-bf16 bought back by hi/lo-split GEMM1 A-operand (removes zin-bf16
// rounding, the largest single source, present even in R9).

typedef unsigned short ushort_t;
typedef unsigned int uint_t;
typedef __attribute__((ext_vector_type(8))) short bf16x8;
typedef __attribute__((ext_vector_type(16))) float f32x16;

#define MFMA32(a, b, c) __builtin_amdgcn_mfma_f32_32x32x16_bf16(a, b, c, 0, 0, 0)

__device__ inline ushort_t f2bf(float f) {
  uint_t u = __builtin_bit_cast(uint_t, f);
  u += 0x7FFFu + ((u >> 16) & 1u);
  return (ushort_t)(u >> 16);
}
__device__ inline float bf2f(uint_t h) {  // low 16 bits
  uint_t u = (h & 0xFFFFu) << 16;
  return __builtin_bit_cast(float, u);
}
__device__ inline uint_t pack2(float a, float b) {
  return (uint_t)f2bf(a) | ((uint_t)f2bf(b) << 16);
}
__device__ inline f32x16 zero16() {
  f32x16 z;
#pragma unroll
  for (int i = 0; i < 16; ++i) z[i] = 0.f;
  return z;
}

// ---------- precompute ----------

// comb[l][c][128] bf16, c = a0|a1<<4|a2<<8
__global__ __launch_bounds__(256) void bond_comb_k(
    const float* __restrict__ bemb, ushort_t* __restrict__ comb)
{
  int idx = blockIdx.x * 256 + threadIdx.x;  // over 5*4096*64
  if (idx >= 5 * 4096 * 64) return;
  int lane = idx & 63, c = (idx >> 6) & 4095, l = idx >> 18;
  const float2* b2 = (const float2*)(bemb + (size_t)l * 3 * 16 * 128);
  float2 e0 = b2[(c & 15) * 64 + lane];
  float2 e1 = b2[(16 + ((c >> 4) & 15)) * 64 + lane];
  float2 e2 = b2[(32 + (c >> 8)) * 64 + lane];
  ((uint_t*)comb)[idx] = pack2(e0.x + e1.x + e2.x, e0.y + e1.y + e2.y);
}

// All 11 weight swizzles in one launch. m<6: K=128,N=256 (w1 x5, linw);
// m>=6: K=256,N=128 (w2 x5).
__global__ __launch_bounds__(256) void swz_all_k(
    const float* __restrict__ w1, const float* __restrict__ linw,
    const float* __restrict__ w2, ushort_t* __restrict__ bswz1,
    ushort_t* __restrict__ bswz2)
{
  int t = blockIdx.x * 256 + threadIdx.x;  // 11*4096
  if (t >= 11 * 4096) return;
  int m = t >> 12, tt = t & 4095, lane = tt & 63;
  if (m < 6) {
    const float* w = (m < 5) ? (w1 + (size_t)m * 32768) : linw;
    ushort_t* o = bswz1 + (size_t)m * 32768;
    int nt = (tt >> 6) & 7, s = tt >> 9;
    int kb = s * 16 + (lane >> 5) * 8, n = nt * 32 + (lane & 31);
    ushort_t tmp[8];
#pragma unroll
    for (int j = 0; j < 8; ++j) tmp[j] = f2bf(w[(size_t)(kb + j) * 256 + n]);
    ((uint4*)o)[tt] = *(uint4*)tmp;
  } else {
    int mm = m - 6;
    const float* w = w2 + (size_t)mm * 32768;
    ushort_t* o = bswz2 + (size_t)mm * 32768;
    int nt = (tt >> 6) & 3, s = tt >> 8;
    int kb = s * 16 + (lane >> 5) * 8, n = nt * 32 + (lane & 31);
    ushort_t tmp[8];
#pragma unroll
    for (int j = 0; j < 8; ++j) tmp[j] = f2bf(w[(size_t)(kb + j) * 128 + n]);
    ((uint4*)o)[tt] = *(uint4*)tmp;
  }
}

// ---------- graph preprocessing ----------

__global__ void zero_int_k(int* p, int n) {
  int i = blockIdx.x * 256 + threadIdx.x;
  if (i < n) p[i] = 0;
}

__global__ void hist_k(const int* __restrict__ ei, int* __restrict__ cnt, int E) {
  int e = blockIdx.x * 256 + threadIdx.x;
  if (e >= E) return;
  atomicAdd(&cnt[ei[E + e]], 1);
}

__global__ __launch_bounds__(256) void block_sum_k(
    const int* __restrict__ cnt, int* __restrict__ bsum, int N)
{
  __shared__ int red[256];
  int t = threadIdx.x, idx = blockIdx.x * 256 + t;
  red[t] = (idx < N) ? cnt[idx] : 0;
  __syncthreads();
  for (int o = 128; o > 0; o >>= 1) {
    if (t < o) red[t] += red[t + o];
    __syncthreads();
  }
  if (t == 0) bsum[blockIdx.x] = red[0];
}

__global__ __launch_bounds__(256) void scan_bsum_k(
    int* __restrict__ bsum, int* __restrict__ rsN, int nb)
{
  __shared__ int s[256];
  int t = threadIdx.x;
  s[t] = (t < nb) ? bsum[t] : 0;
  __syncthreads();
  for (int o = 1; o < 256; o <<= 1) {
    int v = (t >= o) ? s[t - o] : 0;
    __syncthreads();
    s[t] += v;
    __syncthreads();
  }
  if (t < nb) bsum[t] = (t == 0) ? 0 : s[t - 1];
  if (t == nb - 1) *rsN = s[t];
}

__global__ __launch_bounds__(256) void scan_write_k(
    const int* __restrict__ cnt, const int* __restrict__ bsum,
    int* __restrict__ rs, int* __restrict__ cursor, int N)
{
  __shared__ int s[256];
  int t = threadIdx.x, idx = blockIdx.x * 256 + t;
  int v = (idx < N) ? cnt[idx] : 0;
  s[t] = v;
  __syncthreads();
  for (int o = 1; o < 256; o <<= 1) {
    int u = (t >= o) ? s[t - o] : 0;
    __syncthreads();
    s[t] += u;
    __syncthreads();
  }
  int excl = s[t] - v + bsum[blockIdx.x];
  if (idx < N) { rs[idx] = excl; cursor[idx] = excl; }
}

__global__ void scatter_k(const int* __restrict__ ei, const int* __restrict__ ea,
                          int* __restrict__ cursor, uint32_t* __restrict__ sorted, int E)
{
  int e = blockIdx.x * 256 + threadIdx.x;
  if (e >= E) return;
  int src = ei[e], dst = ei[E + e];
  int a0 = ea[e * 3], a1 = ea[e * 3 + 1], a2 = ea[e * 3 + 2];
  int pos = atomicAdd(&cursor[dst], 1);
  sorted[pos] = (uint32_t)src | ((uint32_t)a0 << 16) | ((uint32_t)a1 << 20) | ((uint32_t)a2 << 24);
}

// ---------- node pipeline ----------

// Layer-0 h (no BN): write bf16 directly into hbn. Block 0 zeroes BN1 stats
// for layer 0's agg_gemm1.
__global__ __launch_bounds__(256) void atom_encode_k(
    const int* __restrict__ x, const float* __restrict__ aemb,
    ushort_t* __restrict__ hbn, float* __restrict__ stats, int N)
{
  if (blockIdx.x == 0) {
    stats[threadIdx.x] = 0.f;
    stats[threadIdx.x + 256] = 0.f;
  }
  int idx = blockIdx.x * 256 + threadIdx.x;
  if (idx >= N * 64) return;
  int n = idx >> 6, lane = idx & 63;
  const int* xr = x + n * 9;
  float sx = 0.f, sy = 0.f;
#pragma unroll
  for (int f = 0; f < 9; ++f) {
    float2 e = ((const float2*)(aemb + (size_t)(f * 128 + xr[f]) * 128))[lane];
    sx += e.x; sy += e.y;
  }
  ((uint_t*)hbn)[idx] = pack2(sx, sy);
}

// Materialize hbn = relu(BN(raw fp32)) as bf16, once per layer (layers 1..4).
// Block 0 zeroes BN1 stats (statsZero[0..511]) for the upcoming agg_gemm1.
__global__ __launch_bounds__(256) void bnrelu_k(
    const float* __restrict__ raw, const float* __restrict__ stats2,
    const float* __restrict__ g, const float* __restrict__ bb,
    ushort_t* __restrict__ hbn, float* __restrict__ statsZero,
    float invN, int total)
{
  if (blockIdx.x == 0) {
    statsZero[threadIdx.x] = 0.f;
    statsZero[threadIdx.x + 256] = 0.f;
  }
  int t = blockIdx.x * 256 + threadIdx.x;
  int lane = t & 63;
  int c0 = 2 * lane, c1 = c0 + 1;
  float mu0 = stats2[c0] * invN, mu1 = stats2[c1] * invN;
  float v0 = stats2[128 + c0] * invN - mu0 * mu0;
  float v1 = stats2[128 + c1] * invN - mu1 * mu1;
  float scx = rsqrtf(v0 + 1e-5f) * g[c0];
  float scy = rsqrtf(v1 + 1e-5f) * g[c1];
  float shx = bb[c0] - mu0 * scx;
  float shy = bb[c1] - mu1 * scy;
  int stride = gridDim.x * 256;
  for (int idx = t; idx < total; idx += stride) {
    float2 h = ((const float2*)raw)[idx];
    float hx = fmaxf(fmaf(h.x, scx, shx), 0.f);
    float hy = fmaxf(fmaf(h.y, scy, shy), 0.f);
    ((uint_t*)hbn)[idx] = pack2(hx, hy);
  }
}

// ---------- fused aggregate + GEMM1 ----------
// 512 threads = 8 waves; block owns 64 node rows.
// Phase 1: wave w gathers nodes r = w + 8j (j=0..7); zin row split hi/lo
// bf16 into two XOR-swizzled LDS tiles (As=hi, Al=lo) -> GEMM1 A-operand is
// effectively fp32 (removes the zin bf16 rounding R9 carried).
// Phase 2: wave nt computes cols [nt*32,nt*32+32) x rows 0..63 via acc0/acc1,
// writes z1 = acc + b1 as bf16 into z1bf (ALIASED on raw; block-matched
// bytes), accumulates BN1 stats (R9-exact pairing, one atomicAdd/block/col).
// Block 0 zeroes BN2 stats region (stats[512..767]).
__global__ __launch_bounds__(512, 4) void agg_gemm1_k(
    const ushort_t* __restrict__ hbn, const ushort_t* __restrict__ comb,
    const uint32_t* __restrict__ sorted, const int* __restrict__ rs,
    const float* __restrict__ eps, int layer,
    const ushort_t* __restrict__ bswz, const float* __restrict__ bias,
    ushort_t* __restrict__ z1bf, float* __restrict__ stats, int N)
{
  __shared__ ushort_t As[64 * 128];   // hi, 16 KB
  __shared__ ushort_t Al[64 * 128];   // lo, 16 KB
  int tid = threadIdx.x;
  int wave = tid >> 6, lane = tid & 63;
  int row0 = blockIdx.x * 64;
  if (blockIdx.x == 0 && tid < 256) stats[512 + tid] = 0.f;
  const uint_t* hb = (const uint_t*)hbn;
  const uint_t* cb = ((const uint_t*)comb) + (size_t)layer * 4096 * 64;
  float s_eps = 1.f + eps[layer];
#pragma unroll 1
  for (int j = 0; j < 8; ++j) {
    int r = wave + 8 * j;
    int n = row0 + r;
    int beg = rs[n], end = rs[n + 1];
    float ax = 0.f, ay = 0.f;
    int i = beg;
    for (; i + 16 <= end; i += 16) {
      uint32_t p[16];
#pragma unroll
      for (int jj = 0; jj < 16; ++jj) p[jj] = sorted[i + jj];
      uint_t hv[16], ee[16];
#pragma unroll
      for (int jj = 0; jj < 16; ++jj) {
        hv[jj] = hb[(size_t)(p[jj] & 0xFFFFu) * 64 + lane];
        ee[jj] = cb[(p[jj] >> 16) * 64 + lane];
      }
#pragma unroll
      for (int jj = 0; jj < 16; ++jj) {
        ax += fmaxf(bf2f(hv[jj]) + bf2f(ee[jj]), 0.f);
        ay += fmaxf(bf2f(hv[jj] >> 16) + bf2f(ee[jj] >> 16), 0.f);
      }
    }
    for (; i + 4 <= end; i += 4) {
      uint32_t p[4];
#pragma unroll
      for (int jj = 0; jj < 4; ++jj) p[jj] = sorted[i + jj];
      uint_t hv[4], ee[4];
#pragma unroll
      for (int jj = 0; jj < 4; ++jj) {
        hv[jj] = hb[(size_t)(p[jj] & 0xFFFFu) * 64 + lane];
        ee[jj] = cb[(p[jj] >> 16) * 64 + lane];
      }
#pragma unroll
      for (int jj = 0; jj < 4; ++jj) {
        ax += fmaxf(bf2f(hv[jj]) + bf2f(ee[jj]), 0.f);
        ay += fmaxf(bf2f(hv[jj] >> 16) + bf2f(ee[jj] >> 16), 0.f);
      }
    }
    for (; i < end; ++i) {
      uint32_t p = sorted[i];
      uint_t ee = cb[(p >> 16) * 64 + lane];
      uint_t hv = hb[(size_t)(p & 0xFFFFu) * 64 + lane];
      ax += fmaxf(bf2f(hv) + bf2f(ee), 0.f);
      ay += fmaxf(bf2f(hv >> 16) + bf2f(ee >> 16), 0.f);
    }
    uint_t hn = hb[(size_t)n * 64 + lane];
    float zx = fmaf(s_eps, bf2f(hn), ax);
    float zy = fmaf(s_eps, bf2f(hn >> 16), ay);
    ushort_t hxz = f2bf(zx), hyz = f2bf(zy);
    float lox = zx - bf2f(hxz), loy = zy - bf2f(hyz);
    int c = 2 * lane;
    int scol = (((c >> 3) ^ (r & 15)) << 3) | (c & 7);
    *(uint_t*)&As[r * 128 + scol] = (uint_t)hxz | ((uint_t)hyz << 16);
    *(uint_t*)&Al[r * 128 + scol] = pack2(lox, loy);
  }
  __syncthreads();
  // GEMM1: wave = nt (col tile), acc0 = rows 0..31, acc1 = rows 32..63.
  int lr = lane & 31, half = lane >> 5;
  int nt = wave;
  f32x16 acc0 = zero16(), acc1 = zero16();
  const bf16x8* Bp = (const bf16x8*)bswz;
#pragma unroll
  for (int s = 0; s < 8; ++s) {
    int k = s * 16 + half * 8;
    int scol = ((k >> 3) ^ (lr & 15)) << 3;
    bf16x8 b = Bp[(s * 8 + nt) * 64 + lane];
    bf16x8 ah0 = *(const bf16x8*)&As[lr * 128 + scol];
    bf16x8 al0 = *(const bf16x8*)&Al[lr * 128 + scol];
    bf16x8 ah1 = *(const bf16x8*)&As[(32 + lr) * 128 + scol];
    bf16x8 al1 = *(const bf16x8*)&Al[(32 + lr) * 128 + scol];
    acc0 = MFMA32(ah0, b, acc0);
    acc0 = MFMA32(al0, b, acc0);
    acc1 = MFMA32(ah1, b, acc1);
    acc1 = MFMA32(al1, b, acc1);
  }
  int col = nt * 32 + lr;
  float bv = bias[col];
  float s0 = 0.f, q0 = 0.f;
#pragma unroll
  for (int r2 = 0; r2 < 16; ++r2) {
    int rrow = (r2 & 3) + 8 * (r2 >> 2) + 4 * half;
    float v0 = acc0[r2] + bv;
    float v1 = acc1[r2] + bv;
    z1bf[(size_t)(row0 + rrow) * 256 + col] = f2bf(v0);
    z1bf[(size_t)(row0 + 32 + rrow) * 256 + col] = f2bf(v1);
    s0 += v0 + v1;
    q0 += v0 * v0 + v1 * v1;
  }
  s0 += __shfl_xor(s0, 32);
  q0 += __shfl_xor(q0, 32);
  if (lane < 32) {
    atomicAdd(&stats[col], s0);
    atomicAdd(&stats[256 + col], q0);
  }
}

// ---------- GEMM2 ----------
// rawz is BOTH the z1 bf16 source and the fp32 z2 destination (byte-aliased,
// block-matched: block b reads bytes [b*32K,(b+1)*32K) into LDS before the
// barrier, writes the same bytes after). NO __restrict__ on rawz.
// BN1+relu applied during staging (single post-BN1 bf16 rounding),
// GEMM2 [64,256]@[256,128]+b2 -> raw fp32, accumulate BN2 stats.
__global__ __launch_bounds__(256) void mlp2_k(
    float* rawz, const float* __restrict__ stats1,
    const float* __restrict__ g1, const float* __restrict__ bb1,
    const ushort_t* __restrict__ bswz2, const float* __restrict__ b2,
    float* __restrict__ stats2, float invN)
{
  __shared__ ushort_t Bs[64 * 256];   // 32 KB
  __shared__ float sc1[256], sh1[256];
  int tid = threadIdx.x;
  int wave = tid >> 6, lane = tid & 63;
  int lr = lane & 31, half = lane >> 5;
  int row0 = blockIdx.x * 64;
  {
    float mu = stats1[tid] * invN;
    float var = stats1[256 + tid] * invN - mu * mu;
    float r = rsqrtf(var + 1e-5f) * g1[tid];
    sc1[tid] = r;
    sh1[tid] = bb1[tid] - mu * r;
  }
  __syncthreads();
  {
    const uint4* src = (const uint4*)((const ushort_t*)rawz + (size_t)row0 * 256);
#pragma unroll
    for (int i = 0; i < 8; ++i) {
      int idx = tid + 256 * i;        // 2048 chunks of 8 bf16
      int r = idx >> 5, c = (idx & 31) * 8;
      uint4 v = src[idx];
      float f0 = fmaxf(fmaf(bf2f(v.x), sc1[c], sh1[c]), 0.f);
      float f1 = fmaxf(fmaf(bf2f(v.x >> 16), sc1[c + 1], sh1[c + 1]), 0.f);
      float f2 = fmaxf(fmaf(bf2f(v.y), sc1[c + 2], sh1[c + 2]), 0.f);
      float f3 = fmaxf(fmaf(bf2f(v.y >> 16), sc1[c + 3], sh1[c + 3]), 0.f);
      float f4 = fmaxf(fmaf(bf2f(v.z), sc1[c + 4], sh1[c + 4]), 0.f);
      float f5 = fmaxf(fmaf(bf2f(v.z >> 16), sc1[c + 5], sh1[c + 5]), 0.f);
      float f6 = fmaxf(fmaf(bf2f(v.w), sc1[c + 6], sh1[c + 6]), 0.f);
      float f7 = fmaxf(fmaf(bf2f(v.w >> 16), sc1[c + 7], sh1[c + 7]), 0.f);
      uint4 o;
      o.x = pack2(f0, f1);
      o.y = pack2(f2, f3);
      o.z = pack2(f4, f5);
      o.w = pack2(f6, f7);
      int scol = ((c >> 3) ^ (r & 15)) << 3;
      *(uint4*)&Bs[r * 256 + scol] = o;
    }
  }
  __syncthreads();
  f32x16 acc0 = zero16(), acc1 = zero16();
  {
    const bf16x8* Bp2 = (const bf16x8*)bswz2;
#pragma unroll
    for (int s = 0; s < 16; ++s) {
      int k = s * 16 + half * 8;
      int scol = ((k >> 3) ^ (lr & 15)) << 3;
      bf16x8 a0 = *(const bf16x8*)&Bs[lr * 256 + scol];
      bf16x8 a1 = *(const bf16x8*)&Bs[(32 + lr) * 256 + scol];
      bf16x8 b = Bp2[(s * 4 + wave) * 64 + lane];
      acc0 = MFMA32(a0, b, acc0);
      acc1 = MFMA32(a1, b, acc1);
    }
  }
  int col = wave * 32 + lr;
  float bv = b2[col];
  float s0 = 0.f, q0 = 0.f;
  auto emit = [&](const f32x16& a, int mtb) {
#pragma unroll
    for (int r2 = 0; r2 < 16; ++r2) {
      int row = row0 + mtb + (r2 & 3) + 8 * (r2 >> 2) + 4 * half;
      float v = a[r2] + bv;
      rawz[(size_t)row * 128 + col] = v;
      s0 += v;
      q0 += v * v;
    }
  };
  emit(acc0, 0);
  emit(acc1, 32);
  s0 += __shfl_xor(s0, 32);
  q0 += __shfl_xor(q0, 32);
  if (lane < 32) {
    atomicAdd(&stats2[col], s0);
    atomicAdd(&stats2[128 + col], q0);
  }
}

// Final projection: BN(stats2) on fp32 raw at load (no relu), then
// [64,128]@[128,256]+linb -> fp32 out.
__global__ __launch_bounds__(256) void final_proj_k(
    const float* __restrict__ inf, const ushort_t* __restrict__ bswz,
    const float* __restrict__ bias, const float* __restrict__ stats2,
    const float* __restrict__ g, const float* __restrict__ bb,
    float* __restrict__ outf, float invN)
{
  __shared__ ushort_t As[64 * 128];
  __shared__ float sc[128], sh[128];
  int tid = threadIdx.x;
  int wave = tid >> 6, lane = tid & 63;
  int lr = lane & 31, half = lane >> 5;
  int row0 = blockIdx.x * 64;
  if (tid < 128) {
    int c = tid;
    float mu = stats2[c] * invN;
    float var = stats2[128 + c] * invN - mu * mu;
    float r = rsqrtf(var + 1e-5f) * g[c];
    sc[c] = r;
    sh[c] = bb[c] - mu * r;
  }
  __syncthreads();
  {
    const float4* src = (const float4*)(inf + (size_t)row0 * 128);
#pragma unroll
    for (int i = 0; i < 8; ++i) {
      int idx = tid + 256 * i;
      int r = idx >> 5, c = (idx & 31) * 4;
      float4 v = src[idx];
      v.x = fmaf(v.x, sc[c], sh[c]);
      v.y = fmaf(v.y, sc[c + 1], sh[c + 1]);
      v.z = fmaf(v.z, sc[c + 2], sh[c + 2]);
      v.w = fmaf(v.w, sc[c + 3], sh[c + 3]);
      uint2 o;
      o.x = pack2(v.x, v.y);
      o.y = pack2(v.z, v.w);
      int scol = (((c >> 3) ^ (r & 15)) << 3) | (c & 7);
      *(uint2*)&As[r * 128 + scol] = o;
    }
  }
  __syncthreads();
  int nt0 = wave * 2, nt1 = nt0 + 1;
  f32x16 acc00 = zero16(), acc01 = zero16(), acc10 = zero16(), acc11 = zero16();
  const bf16x8* Bp = (const bf16x8*)bswz;
#pragma unroll
  for (int s = 0; s < 8; ++s) {
    int k = s * 16 + half * 8;
    int scol = ((k >> 3) ^ (lr & 15)) << 3;
    bf16x8 a0 = *(const bf16x8*)&As[lr * 128 + scol];
    bf16x8 a1 = *(const bf16x8*)&As[(32 + lr) * 128 + scol];
    bf16x8 b0 = Bp[(s * 8 + nt0) * 64 + lane];
    bf16x8 b1 = Bp[(s * 8 + nt1) * 64 + lane];
    acc00 = MFMA32(a0, b0, acc00);
    acc10 = MFMA32(a1, b0, acc10);
    acc01 = MFMA32(a0, b1, acc01);
    acc11 = MFMA32(a1, b1, acc11);
  }
  int col0 = nt0 * 32 + lr, col1 = nt1 * 32 + lr;
  float bv0 = bias[col0], bv1 = bias[col1];
  auto emit = [&](const f32x16& a, int mtb, int col, float bv) {
#pragma unroll
    for (int r2 = 0; r2 < 16; ++r2) {
      int row = row0 + mtb + (r2 & 3) + 8 * (r2 >> 2) + 4 * half;
      outf[(size_t)row * 256 + col] = a[r2] + bv;
    }
  };
  emit(acc00, 0, col0, bv0);
  emit(acc10, 32, col0, bv0);
  emit(acc01, 0, col1, bv1);
  emit(acc11, 32, col1, bv1);
}

extern "C" void kernel_launch(void* const* d_in, const int* in_sizes, int n_in,
                              void* d_out, int out_size, void* d_ws, size_t ws_size,
                              hipStream_t stream)
{
  const int* x = (const int*)d_in[0];
  const int* ei = (const int*)d_in[1];
  const int* ea = (const int*)d_in[2];
  const float* aemb = (const float*)d_in[3];
  const float* bemb = (const float*)d_in[4];
  const float* eps = (const float*)d_in[5];
  const float* w1 = (const float*)d_in[6];
  const float* b1 = (const float*)d_in[7];
  const float* bn1g = (const float*)d_in[8];
  const float* bn1b = (const float*)d_in[9];
  const float* w2 = (const float*)d_in[10];
  const float* b2 = (const float*)d_in[11];
  const float* bng = (const float*)d_in[12];
  const float* bnb = (const float*)d_in[13];
  const float* linw = (const float*)d_in[14];
  const float* linb = (const float*)d_in[15];
  int N = in_sizes[0] / 9;   // 40000
  int E = in_sizes[1] / 2;   // 640000
  int nb = (N + 255) / 256;

  char* ws = (char*)d_ws;
  size_t off = 0;
  auto alloc = [&](size_t bytes) {
    void* p = ws + off;
    off += (bytes + 255) & ~(size_t)255;
    return p;
  };
  // raw doubles as z1-bf16 (byte-aliased, block-matched; see agg_gemm1/mlp2).
  float* raw = (float*)alloc((size_t)N * 128 * 4);          // 20.48 MB
  ushort_t* hbn = (ushort_t*)alloc((size_t)N * 128 * 2);    // 10.24 MB
  ushort_t* comb = (ushort_t*)alloc((size_t)5 * 4096 * 128 * 2);  // 5.24 MB
  ushort_t* bswz1 = (ushort_t*)alloc((size_t)6 * 32768 * 2);
  ushort_t* bswz2 = (ushort_t*)alloc((size_t)5 * 32768 * 2);
  uint32_t* sorted = (uint32_t*)alloc((size_t)E * 4);       // 2.56 MB
  int* rs = (int*)alloc((size_t)(N + 1) * 4);
  int* cursor = (int*)alloc((size_t)N * 4);
  int* cnt = (int*)alloc((size_t)N * 4);
  int* bsum = (int*)alloc((size_t)nb * 4);
  float* stats = (float*)alloc(768 * 4);  // [sum1:256][sq1:256][sum2:128][sq2:128]
  float invN = 1.f / (float)N;

  bond_comb_k<<<(5 * 4096 * 64 + 255) / 256, 256, 0, stream>>>(bemb, comb);
  swz_all_k<<<(11 * 4096 + 255) / 256, 256, 0, stream>>>(w1, linw, w2, bswz1, bswz2);

  atom_encode_k<<<(N * 64 + 255) / 256, 256, 0, stream>>>(x, aemb, hbn, stats, N);
  zero_int_k<<<(N + 255) / 256, 256, 0, stream>>>(cnt, N);
  hist_k<<<(E + 255) / 256, 256, 0, stream>>>(ei, cnt, E);
  block_sum_k<<<nb, 256, 0, stream>>>(cnt, bsum, N);
  scan_bsum_k<<<1, 256, 0, stream>>>(bsum, rs + N, nb);
  scan_write_k<<<nb, 256, 0, stream>>>(cnt, bsum, rs, cursor, N);
  scatter_k<<<(E + 255) / 256, 256, 0, stream>>>(ei, ea, cursor, sorted, E);

  for (int l = 0; l < 5; ++l) {
    if (l > 0) {
      bnrelu_k<<<2048, 256, 0, stream>>>(
          raw, stats + 512, bng + (size_t)(l - 1) * 128,
          bnb + (size_t)(l - 1) * 128, hbn, stats, invN, N * 64);
    }
    agg_gemm1_k<<<N / 64, 512, 0, stream>>>(
        hbn, comb, sorted, rs, eps, l,
        bswz1 + (size_t)l * 32768, b1 + (size_t)l * 256,
        (ushort_t*)raw, stats, N);
    mlp2_k<<<N / 64, 256, 0, stream>>>(
        raw, stats, bn1g + (size_t)l * 256, bn1b + (size_t)l * 256,
        bswz2 + (size_t)l * 32768, b2 + (size_t)l * 128,
        stats + 512, invN);
  }
  final_proj_k<<<N / 64, 256, 0, stream>>>(
      raw, bswz1 + (size_t)5 * 32768, linb, stats + 512,
      bng + (size_t)4 * 128, bnb + (size_t)4 * 128, (float*)d_out, invN);
}